// Round 16
// baseline (558.007 us; speedup 1.0000x reference)
//
#include <hip/hip_runtime.h>

// Problem constants: V=50000 D=300 H=512 CO=100 B=64 S=32 W=128
// Sentences: B*S = 2048, tokens/sentence = 128.
//
// R16 = R13 with conv position-split for occupancy: grid 4096 = 2048 x 2
// halves; B-tile 68 rows (64 pos + 4 halo) x 304 bf16 = 41344B -> 3 blocks/CU
// -> 6 waves/SIMD (was 2 blocks/4 waves at 80KB). acc[2] = 32 AGPR (2
// pos-tiles). bf-reads/MFMA unchanged (1:1); af reuse 1:4 -> 1:2 (af stream
// 3.7GB over L2, ~25TB/s < ceiling). Unlike R5's failed split (16x16: both
// reuses halved), only af pays here. Per-half max -> sentP[sid][half][304],
// consumers fmax halves (R4/R5-verified plumbing). XOR swizzle flips bits 4-6
// only -> stays in 128B bucket -> max byte 41343, LDSBYTES=41344 exact.
// Rest = R13: bf16 emb gather, A [g][ks19][lane][8], rnn v3, xigh0 4-row,
// merged prep.

#define LDSK     304
#define LDSROWB  608              // row stride bytes
#define LDSBYTES 41344            // 68*608; XOR swizzle is 128B-bucket-local

typedef __bf16   bf16x8 __attribute__((ext_vector_type(8)));
typedef float    f32x16 __attribute__((ext_vector_type(16)));
typedef _Float16 h2v    __attribute__((ext_vector_type(2)));

#define MFMA32(a, b, c) __builtin_amdgcn_mfma_f32_32x32x16_bf16((a), (b), (c), 0, 0, 0)

__device__ __forceinline__ unsigned int packf16(float a, float b) {
  h2v h; h[0] = (_Float16)a; h[1] = (_Float16)b;
  return __builtin_bit_cast(unsigned int, h);
}

// ---------------- P: merged prep. Blocks [0,7325): emb->bf16; [7325,9149): convw; [9149,9405): whh
__global__ void prep_all(const float* __restrict__ e, __bf16* __restrict__ eh,
                         const float* __restrict__ w3, const float* __restrict__ w4,
                         const float* __restrict__ w5, __bf16* __restrict__ Aw32,
                         const float* __restrict__ whf, const float* __restrict__ whb,
                         uint4* __restrict__ Wq) {
  const int bid = blockIdx.x;
  if (bid < 7325) {
    long i = ((long)bid * 256 + threadIdx.x) * 8;
    if (i >= 15000000L) return;
    float4 a = *(const float4*)(e + i);
    float4 b = *(const float4*)(e + i + 4);
    union { __bf16 h[8]; uint4 u; } pk;
    pk.h[0] = (__bf16)a.x; pk.h[1] = (__bf16)a.y; pk.h[2] = (__bf16)a.z; pk.h[3] = (__bf16)a.w;
    pk.h[4] = (__bf16)b.x; pk.h[5] = (__bf16)b.y; pk.h[6] = (__bf16)b.z; pk.h[7] = (__bf16)b.w;
    *(uint4*)(eh + i) = pk.u;
  } else if (bid < 9149) {
    // Aw32[((g*19 + ks)*64 + lane)*8 + i] = W[ch=cg*32+(lane&31)][k=ks*16+(lane>>5)*8+i]
    int idx = (bid - 7325) * 256 + threadIdx.x;
    if (idx >= 48 * 19 * 64 * 8) return;
    int i    = idx & 7;
    int lane = (idx >> 3) & 63;
    int rem  = idx >> 9;            // g*19 + ks
    int ks   = rem % 19, g = rem / 19;
    int kc, cg, j; const float* w;
    if (g < 12)      { kc = 3; cg = g / 3;        j = g % 3;        w = w3; }
    else if (g < 28) { kc = 4; cg = (g - 12) / 4; j = (g - 12) % 4; w = w4; }
    else             { kc = 5; cg = (g - 28) / 5; j = (g - 28) % 5; w = w5; }
    int ch = cg * 32 + (lane & 31);
    int k  = ks * 16 + (lane >> 5) * 8 + i;
    float v = 0.f;
    if (ch < 100 && k < 300) v = w[(ch * kc + j) * 300 + k];
    Aw32[idx] = (__bf16)v;
  } else {
    // Wq[dir][kq][tid]: x=pack(W[tid][4kq],+1) y=pack(W[tid+256][4kq],+1)
    //                   z=pack(W[tid][4kq+2],+3) w=pack(W[tid+256][4kq+2],+3)
    int idx = (bid - 9149) * 256 + threadIdx.x;
    if (idx >= 2 * 128 * 256) return;
    int dir = idx >> 15;
    int rem = idx & 32767;
    int kq = rem >> 8, tid = rem & 255;
    const float* W = dir ? whb : whf;
    const float* r0 = W + (size_t)tid * 512 + 4 * kq;
    const float* r1 = W + (size_t)(tid + 256) * 512 + 4 * kq;
    uint4 o;
    o.x = packf16(r0[0], r0[1]);
    o.y = packf16(r1[0], r1[1]);
    o.z = packf16(r0[2], r0[3]);
    o.w = packf16(r1[2], r1[3]);
    Wq[idx] = o;
  }
}

// ---------------- conv chunk: ONE ch-group, 2 pos-tiles (32 AGPR acc), runtime kc -------------
__device__ __forceinline__ void conv_chunk1(const char* ldsc, const __bf16* __restrict__ Aw32,
                                            int GB, int kc, int cg,
                                            const float* __restrict__ bias,
                                            int colbase, int pmax, int pbase,
                                            float* __restrict__ prow, int lane) {
  const int m32 = lane & 31, hi = lane >> 5;
  f32x16 acc[2];
#pragma unroll
  for (int n = 0; n < 2; ++n)
#pragma unroll
    for (int e = 0; e < 16; ++e) acc[n][e] = 0.f;

  for (int j = 0; j < kc; ++j) {                     // runtime j (R4 lesson: no full unroll)
    const int row0 = m32 + j;
    const int mask = (row0 & 7) << 4;                // rows 32 apart share (row&7)
    const int rowbyte = row0 * LDSROWB + hi * 16;
    const __bf16* a0 = Aw32 + (size_t)(GB + cg * kc + j) * (19 * 512) + lane * 8;
#pragma unroll 2
    for (int ks = 0; ks < 19; ++ks) {
      bf16x8 bf[2];
#pragma unroll
      for (int nt = 0; nt < 2; ++nt) {
        int addr = rowbyte + nt * (32 * LDSROWB) + ks * 32;
        bf[nt] = *(const bf16x8*)(ldsc + (addr ^ mask));
      }
      bf16x8 af = *(const bf16x8*)(a0 + ks * 512);
#pragma unroll
      for (int nt = 0; nt < 2; ++nt)
        acc[nt] = MFMA32(af, bf[nt], acc[nt]);
    }
  }
  // epilogue: mask invalid positions, partial max over this half's 64 positions,
  // then relu(max+bias) is applied at the CONSUMER after fmax of halves?  No --
  // relu/bias commute with max (monotone), but halves combine by max BEFORE
  // bias+relu; store raw partial max here, consumer does fmax then bias+relu?
  // Keep it simple & verified (R5 scheme): store relu(max+bias) per half;
  // since relu(max(a,b)+c) = max(relu(a+c),relu(b+c)), consumer fmax of the
  // two relu'd halves is EXACT.
  float m[16];
#pragma unroll
  for (int r = 0; r < 16; ++r) m[r] = -3.0e38f;
#pragma unroll
  for (int nt = 0; nt < 2; ++nt) {
    int p = pbase + nt * 32 + m32;
    bool valid = (p <= pmax);
#pragma unroll
    for (int r = 0; r < 16; ++r)
      m[r] = fmaxf(m[r], valid ? acc[nt][r] : -3.0e38f);
  }
#pragma unroll
  for (int r = 0; r < 16; ++r) {
#pragma unroll
    for (int d = 1; d < 32; d <<= 1) m[r] = fmaxf(m[r], __shfl_xor(m[r], d, 64));
  }
  if (m32 == 0) {
#pragma unroll
    for (int r = 0; r < 16; ++r) {
      int ch = cg * 32 + (r & 3) + 8 * (r >> 2) + 4 * hi;
      if (ch < 100) prow[colbase + ch] = fmaxf(m[r] + bias[ch], 0.f);
    }
  }
}

// ---------------- K1: per-half conv+relu+maxpool -> sentP[2048][2][304] f32 -------------------
__global__ void __launch_bounds__(512, 6)
conv_kernel(const int* __restrict__ tok, const __bf16* __restrict__ embh,
            const __bf16* __restrict__ Aw32,
            const float* __restrict__ b3, const float* __restrict__ b4, const float* __restrict__ b5,
            float* __restrict__ sentP) {
  extern __shared__ __bf16 lds[];          // LDSBYTES (41344)
  char* ldsc = (char*)lds;
  const int bid = blockIdx.x, tid = threadIdx.x;
  const int sid = bid >> 1, half = bid & 1;
  const int* t0 = tok + sid * 128 + half * 64;
  const char* eb = (const char*)embh;
  const int nrows = half ? 64 : 68;        // half0 stages 4 real spill rows; half1 zero halo
  // tail zeroing rows 0..67 at bytes [600,608)
  if (tid < 68) {
    *(uint2*)(ldsc + ((tid * LDSROWB + 600) ^ ((tid & 7) << 4))) = (uint2){0u, 0u};
  }
  // half1: zero halo rows 64..67 (full rows)
  if (half) {
    for (int i = tid; i < 4 * 75; i += 512) {
      int r = 64 + i / 75, q = i - (i / 75) * 75;
      *(uint2*)(ldsc + ((r * LDSROWB + q * 8) ^ ((r & 7) << 4))) = (uint2){0u, 0u};
    }
  }
  // gather: 75 uint2 (8B) per 600B bf16 row
  for (int i = tid; i < nrows * 75; i += 512) {
    int r = i / 75, q = i - r * 75;
    long tk = (long)t0[r];
    uint2 v = *(const uint2*)(eb + tk * 600L + q * 8);
    *(uint2*)(ldsc + ((r * LDSROWB + q * 8) ^ ((r & 7) << 4))) = v;
  }
  __syncthreads();
  const int wave = tid >> 6, lane = tid & 63;
  const int pbase = half * 64;
  float* prow = sentP + (size_t)(sid * 2 + half) * 304;
  // waves 0-3: conv5 cg=wave then conv3 cg=wave; waves 4-7: conv4 cg=wave-4.
  if (wave < 4) {
    conv_chunk1(ldsc, Aw32, 28, 5, wave, b5, 200, 123, pbase, prow, lane);
    conv_chunk1(ldsc, Aw32,  0, 3, wave, b3,   0, 125, pbase, prow, lane);
  } else {
    conv_chunk1(ldsc, Aw32, 12, 4, wave - 4, b4, 100, 124, pbase, prow, lane);
  }
}

// ---------------- K2: blocks 0..511 = xig (4 rows) ; 512..527 = h0 (4 rows) -------------------
__global__ void xigh0_kernel(const float* __restrict__ sentP,
                             const float* __restrict__ pw, const float* __restrict__ pb,
                             const float* __restrict__ wf, const float* __restrict__ wb,
                             const float* __restrict__ bif, const float* __restrict__ bhf,
                             const float* __restrict__ bib, const float* __restrict__ bhb,
                             const float* __restrict__ iw, const float* __restrict__ ib,
                             float* __restrict__ G, float* __restrict__ h0) {
  __shared__ float s[4][300];
  __shared__ float xi[4][304];
  const int tid = threadIdx.x;
  if (blockIdx.x < 512) {
    const int rb = blockIdx.x * 4;
    for (int i = tid; i < 4 * 300; i += 256) {
      int r = i / 300, c = i - r * 300;
      const float* p2 = sentP + (size_t)(rb + r) * 608;
      s[r][c] = fmaxf(p2[c], p2[304 + c]);
    }
    __syncthreads();
    for (int o = tid; o < 300; o += 256) {
      const float* w = pw + o * 300;
      float bvv = pb[o];
      float a[4];
#pragma unroll
      for (int r = 0; r < 4; ++r) a[r] = bvv;
      for (int k = 0; k < 300; k += 4) {
        float4 wv = *(const float4*)(w + k);
#pragma unroll
        for (int r = 0; r < 4; ++r)
          a[r] += wv.x * s[r][k] + wv.y * s[r][k + 1] + wv.z * s[r][k + 2] + wv.w * s[r][k + 3];
      }
#pragma unroll
      for (int r = 0; r < 4; ++r) xi[r][o] = a[r];
    }
    __syncthreads();
    for (int o = tid; o < 1024; o += 256) {
      int dir = o >> 9, oo = o & 511;
      const float* w = (dir ? wb : wf) + oo * 300;
      float bvv = dir ? (bib[oo] + bhb[oo]) : (bif[oo] + bhf[oo]);
      float a[4];
#pragma unroll
      for (int r = 0; r < 4; ++r) a[r] = bvv;
      for (int k = 0; k < 300; k += 4) {
        float4 wv = *(const float4*)(w + k);
#pragma unroll
        for (int r = 0; r < 4; ++r)
          a[r] += wv.x * xi[r][k] + wv.y * xi[r][k + 1] + wv.z * xi[r][k + 2] + wv.w * xi[r][k + 3];
      }
#pragma unroll
      for (int r = 0; r < 4; ++r) G[(rb + r) * 1024 + o] = a[r];
    }
  } else {
    const int bb = (blockIdx.x - 512) * 4;
    for (int i = tid; i < 4 * 300; i += 256) {
      int r = i / 300, c = i - r * 300;
      const float* p2 = sentP + (size_t)((bb + r) * 32) * 608;
      s[r][c] = fmaxf(p2[c], p2[304 + c]);
    }
    __syncthreads();
    for (int o = tid; o < 512; o += 256) {
      const float* w = iw + o * 300;
      float bvv = ib[o];
      float a[4];
#pragma unroll
      for (int r = 0; r < 4; ++r) a[r] = bvv;
      for (int k = 0; k < 300; k += 4) {
        float4 wv = *(const float4*)(w + k);
#pragma unroll
        for (int r = 0; r < 4; ++r)
          a[r] += wv.x * s[r][k] + wv.y * s[r][k + 1] + wv.z * s[r][k + 2] + wv.w * s[r][k + 3];
      }
#pragma unroll
      for (int r = 0; r < 4; ++r) h0[(bb + r) * 512 + o] = a[r];
    }
  }
}

// ---------------- K4: rnn v3 -- 64 blocks x 1024 thr, 2 chains/block, 4-way k-split -----------
#if __has_builtin(__builtin_amdgcn_fdot2)
#define FDOT2(a, b, c) __builtin_amdgcn_fdot2((a), (b), (c), false)
#else
static __device__ __forceinline__ float FDOT2(h2v a, h2v b, float c) {
  return c + (float)a[0] * (float)b[0] + (float)a[1] * (float)b[1];
}
#endif
__device__ __forceinline__ h2v as_h2(unsigned int u) { return __builtin_bit_cast(h2v, u); }

__global__ void __launch_bounds__(1024)
rnn_kernel(const uint4* __restrict__ Wq, const float* __restrict__ G,
           const float* __restrict__ h0, float* __restrict__ H) {
  const int blk = blockIdx.x, tid = threadIdx.x;
  const int dir = blk >> 5, b0 = (blk & 31) * 2;   // chains b0, b0+1
  const int o = tid & 255, kh = (tid >> 8) & 3;    // o-slot, k-quarter
  __shared__ float hs[2][512];
  __shared__ uint2 h2p[2][128];                    // h2p[c][kq] packs h[4kq..4kq+3]
  __shared__ float part[4][2][512];                // [kh][chain][out]
  {
    int c = tid >> 9, oo = tid & 511;
    hs[c][oo] = h0[(b0 + c) * 512 + oo];
  }
  __syncthreads();
  const uint4* W = Wq + (size_t)dir * (128 * 256);
  for (int t = 0; t < 32; ++t) {
    if (tid < 256) {
      int c = tid >> 7, kq = tid & 127;
      h2p[c][kq] = (uint2){packf16(hs[c][4 * kq], hs[c][4 * kq + 1]),
                           packf16(hs[c][4 * kq + 2], hs[c][4 * kq + 3])};
    }
    __syncthreads();
    float a00 = 0.f, a01 = 0.f, a10 = 0.f, a11 = 0.f;   // [chain][out-half]
    const int kb = kh * 32;
#pragma unroll 4
    for (int kk = 0; kk < 32; ++kk) {
      int kq = kb + kk;
      uint4 w = W[kq * 256 + o];                   // one W load feeds both chains
      uint2 p0 = h2p[0][kq], p1 = h2p[1][kq];
      a00 = FDOT2(as_h2(w.x), as_h2(p0.x), a00); a00 = FDOT2(as_h2(w.z), as_h2(p0.y), a00);
      a01 = FDOT2(as_h2(w.y), as_h2(p0.x), a01); a01 = FDOT2(as_h2(w.w), as_h2(p0.y), a01);
      a10 = FDOT2(as_h2(w.x), as_h2(p1.x), a10); a10 = FDOT2(as_h2(w.z), as_h2(p1.y), a10);
      a11 = FDOT2(as_h2(w.y), as_h2(p1.x), a11); a11 = FDOT2(as_h2(w.w), as_h2(p1.y), a11);
    }
    part[kh][0][o] = a00; part[kh][0][o + 256] = a01;
    part[kh][1][o] = a10; part[kh][1][o + 256] = a11;
    __syncthreads();
    {
      int c = tid >> 9, oo = tid & 511;
      const float* g = G + (size_t)((b0 + c) * 32 + t) * 1024 + dir * 512;
      float s = g[oo] + ((part[0][c][oo] + part[1][c][oo]) + (part[2][c][oo] + part[3][c][oo]));
      float n = tanhf(s);
      hs[c][oo] = n;
      H[(size_t)((dir * 64 + b0 + c) * 32 + t) * 512 + oo] = n;
    }
    __syncthreads();
  }
}

// ---------------- K5: preds = [hf;hb] @ cls_w^T + cls_b -> out[64][32][5] ---------------------
__global__ void pred_kernel(const float* __restrict__ H, const float* __restrict__ cw,
                            const float* __restrict__ cb, float* __restrict__ out) {
  const int bt = blockIdx.x * 4 + (threadIdx.x >> 6);   // 4 bt per 256-thread block
  const int lane = threadIdx.x & 63;
  const int b = bt >> 5, t = bt & 31;
  const float* hf = H + ((size_t)(b * 32 + t)) * 512;
  const float* hb = H + ((size_t)((64 + b) * 32 + t)) * 512;
  for (int c = 0; c < 5; ++c) {
    const float* w = cw + c * 1024;
    float a = 0.f;
    for (int o = lane; o < 512; o += 64) a += w[o] * hf[o] + w[512 + o] * hb[o];
#pragma unroll
    for (int d = 32; d; d >>= 1) a += __shfl_down(a, d, 64);
    if (lane == 0) out[bt * 5 + c] = a + cb[c];
  }
}

// ------------------------------------------------------------------------------------------------
extern "C" void kernel_launch(void* const* d_in, const int* in_sizes, int n_in,
                              void* d_out, int out_size, void* d_ws, size_t ws_size,
                              hipStream_t stream) {
  const int*   tok  = (const int*)d_in[0];
  const float* emb  = (const float*)d_in[1];
  const float* w3   = (const float*)d_in[2];
  const float* b3   = (const float*)d_in[3];
  const float* w4   = (const float*)d_in[4];
  const float* b4   = (const float*)d_in[5];
  const float* w5   = (const float*)d_in[6];
  const float* b5   = (const float*)d_in[7];
  const float* pw   = (const float*)d_in[8];
  const float* pb   = (const float*)d_in[9];
  const float* iw   = (const float*)d_in[10];
  const float* ib   = (const float*)d_in[11];
  const float* wihf = (const float*)d_in[12];
  const float* whhf = (const float*)d_in[13];
  const float* bihf = (const float*)d_in[14];
  const float* bhhf = (const float*)d_in[15];
  const float* wihb = (const float*)d_in[16];
  const float* whhb = (const float*)d_in[17];
  const float* bihb = (const float*)d_in[18];
  const float* bhhb = (const float*)d_in[19];
  const float* cw   = (const float*)d_in[20];
  const float* cb   = (const float*)d_in[21];
  float* out = (float*)d_out;

  // ws layout. embh (28.6MB) ALIASES the G/h0/H region: conv finishes reading
  // embh before xigh0/rnn write G/h0/H (stream-ordered), and prep_all rewrites
  // embh at the start of every call. Max ws use ~36.6MB.
  char* ws = (char*)d_ws;
  __bf16* Aw32  = (__bf16*)(ws);                        //  0MB: 48*19*512*2 = 934 KB
  uint4* Wq     = (uint4*)(ws +  1u * 1024 * 1024);     //  1MB: 1 MB
  float* sentP  = (float*)(ws +  2u * 1024 * 1024);     //  2MB: 2048*608*4 = 4.98 MB
  __bf16* embh  = (__bf16*)(ws + 8u * 1024 * 1024);     //  8MB: 50000*300*2 = 28.6MB (alias)
  float* G      = (float*)(ws +  8u * 1024 * 1024);     //  8MB: 8 MB   (alias of embh)
  float* h0     = (float*)(ws + 16u * 1024 * 1024);     // 16MB: 128 KB (alias of embh)
  float* H      = (float*)(ws + 17u * 1024 * 1024);     // 17MB: 8.4 MB (alias of embh)

  prep_all<<<9405, 256, 0, stream>>>(emb, embh, w3, w4, w5, Aw32, whhf, whhb, Wq);

  conv_kernel<<<4096, 512, LDSBYTES, stream>>>(tok, embh, Aw32, b3, b4, b5, sentP);

  xigh0_kernel<<<528, 256, 0, stream>>>(sentP, pw, pb, wihf, wihb, bihf, bhhf, bihb, bhhb,
                                        iw, ib, G, h0);
  rnn_kernel<<<64, 1024, 0, stream>>>(Wq, G, h0, H);
  pred_kernel<<<512, 256, 0, stream>>>(H, cw, cb, out);
}

// Round 17
// 527.503 us; speedup vs baseline: 1.0578x; 1.0578x over previous
//
#include <hip/hip_runtime.h>

// Problem constants: V=50000 D=300 H=512 CO=100 B=64 S=32 W=128
// Sentences: B*S = 2048, tokens/sentence = 128.
//
// R17 = R13 verbatim (best verified: 527.9us, reproduced twice).
// R16's position-split raised occupancy 37->53% with conv time INVARIANT ->
// conv is saturated on the shared LDS-read/MFMA pipe pair (1KB ds_read_b128
// per MFMA caps MfmaUtil near ~50%; measured 43-45% in both configs), not
// latency-bound. Split's tail costs (+30us) reverted.
// Conv core (R11): one cg32/acc-phase -> 64 AGPR acc, ~56 VGPR, 4 waves/SIMD
// (512thr x 2 blocks/CU); B-tile 132x304 bf16 XOR-swizzled; bf16 emb gather;
// A [g][ks19][lane][8] L2-resident; rnn v3 (64x1024, 2 chains, 4-way k-split);
// xigh0 4-row split; merged prep.

#define LDSK     304
#define LDSROWB  608              // row stride bytes
#define LDSBYTES 80256            // 132*608

typedef __bf16   bf16x8 __attribute__((ext_vector_type(8)));
typedef float    f32x16 __attribute__((ext_vector_type(16)));
typedef _Float16 h2v    __attribute__((ext_vector_type(2)));

#define MFMA32(a, b, c) __builtin_amdgcn_mfma_f32_32x32x16_bf16((a), (b), (c), 0, 0, 0)

__device__ __forceinline__ unsigned int packf16(float a, float b) {
  h2v h; h[0] = (_Float16)a; h[1] = (_Float16)b;
  return __builtin_bit_cast(unsigned int, h);
}

// ---------------- P: merged prep. Blocks [0,7325): emb->bf16; [7325,9149): convw; [9149,9405): whh
__global__ void prep_all(const float* __restrict__ e, __bf16* __restrict__ eh,
                         const float* __restrict__ w3, const float* __restrict__ w4,
                         const float* __restrict__ w5, __bf16* __restrict__ Aw32,
                         const float* __restrict__ whf, const float* __restrict__ whb,
                         uint4* __restrict__ Wq) {
  const int bid = blockIdx.x;
  if (bid < 7325) {
    long i = ((long)bid * 256 + threadIdx.x) * 8;
    if (i >= 15000000L) return;
    float4 a = *(const float4*)(e + i);
    float4 b = *(const float4*)(e + i + 4);
    union { __bf16 h[8]; uint4 u; } pk;
    pk.h[0] = (__bf16)a.x; pk.h[1] = (__bf16)a.y; pk.h[2] = (__bf16)a.z; pk.h[3] = (__bf16)a.w;
    pk.h[4] = (__bf16)b.x; pk.h[5] = (__bf16)b.y; pk.h[6] = (__bf16)b.z; pk.h[7] = (__bf16)b.w;
    *(uint4*)(eh + i) = pk.u;
  } else if (bid < 9149) {
    // Aw32[((g*19 + ks)*64 + lane)*8 + i] = W[ch=cg*32+(lane&31)][k=ks*16+(lane>>5)*8+i]
    int idx = (bid - 7325) * 256 + threadIdx.x;
    if (idx >= 48 * 19 * 64 * 8) return;
    int i    = idx & 7;
    int lane = (idx >> 3) & 63;
    int rem  = idx >> 9;            // g*19 + ks
    int ks   = rem % 19, g = rem / 19;
    int kc, cg, j; const float* w;
    if (g < 12)      { kc = 3; cg = g / 3;        j = g % 3;        w = w3; }
    else if (g < 28) { kc = 4; cg = (g - 12) / 4; j = (g - 12) % 4; w = w4; }
    else             { kc = 5; cg = (g - 28) / 5; j = (g - 28) % 5; w = w5; }
    int ch = cg * 32 + (lane & 31);
    int k  = ks * 16 + (lane >> 5) * 8 + i;
    float v = 0.f;
    if (ch < 100 && k < 300) v = w[(ch * kc + j) * 300 + k];
    Aw32[idx] = (__bf16)v;
  } else {
    // Wq[dir][kq][tid]: x=pack(W[tid][4kq],+1) y=pack(W[tid+256][4kq],+1)
    //                   z=pack(W[tid][4kq+2],+3) w=pack(W[tid+256][4kq+2],+3)
    int idx = (bid - 9149) * 256 + threadIdx.x;
    if (idx >= 2 * 128 * 256) return;
    int dir = idx >> 15;
    int rem = idx & 32767;
    int kq = rem >> 8, tid = rem & 255;
    const float* W = dir ? whb : whf;
    const float* r0 = W + (size_t)tid * 512 + 4 * kq;
    const float* r1 = W + (size_t)(tid + 256) * 512 + 4 * kq;
    uint4 o;
    o.x = packf16(r0[0], r0[1]);
    o.y = packf16(r1[0], r1[1]);
    o.z = packf16(r0[2], r0[3]);
    o.w = packf16(r1[2], r1[3]);
    Wq[idx] = o;
  }
}

// ---------------- conv chunk: ONE ch-group (64 AGPR acc), 4 pos-tiles, runtime kc -------------
__device__ __forceinline__ void conv_chunk1(const char* ldsc, const __bf16* __restrict__ Aw32,
                                            int GB, int kc, int cg,
                                            const float* __restrict__ bias,
                                            int colbase, int pmax,
                                            float* __restrict__ srow, int lane) {
  const int m32 = lane & 31, hi = lane >> 5;
  f32x16 acc[4];
#pragma unroll
  for (int n = 0; n < 4; ++n)
#pragma unroll
    for (int e = 0; e < 16; ++e) acc[n][e] = 0.f;

  for (int j = 0; j < kc; ++j) {                     // runtime j (R4 lesson: no full unroll)
    const int row0 = m32 + j;
    const int mask = (row0 & 7) << 4;                // rows nt*32 apart share (row&7)
    const int rowbyte = row0 * LDSROWB + hi * 16;
    const __bf16* a0 = Aw32 + (size_t)(GB + cg * kc + j) * (19 * 512) + lane * 8;
#pragma unroll 2
    for (int ks = 0; ks < 19; ++ks) {
      bf16x8 bf[4];
#pragma unroll
      for (int nt = 0; nt < 4; ++nt) {
        int addr = rowbyte + nt * (32 * LDSROWB) + ks * 32;
        bf[nt] = *(const bf16x8*)(ldsc + (addr ^ mask));
      }
      bf16x8 af = *(const bf16x8*)(a0 + ks * 512);
#pragma unroll
      for (int nt = 0; nt < 4; ++nt)
        acc[nt] = MFMA32(af, bf[nt], acc[nt]);
    }
  }
  // epilogue: mask invalid positions, max over positions, then relu(max + bias).
  // C layout: col(position) = lane&31, row(channel-in-32) = (r&3) + 8*(r>>2) + 4*hi.
  float m[16];
#pragma unroll
  for (int r = 0; r < 16; ++r) m[r] = -3.0e38f;
#pragma unroll
  for (int nt = 0; nt < 4; ++nt) {
    int p = nt * 32 + m32;
    bool valid = (p <= pmax);
#pragma unroll
    for (int r = 0; r < 16; ++r)
      m[r] = fmaxf(m[r], valid ? acc[nt][r] : -3.0e38f);
  }
#pragma unroll
  for (int r = 0; r < 16; ++r) {
#pragma unroll
    for (int d = 1; d < 32; d <<= 1) m[r] = fmaxf(m[r], __shfl_xor(m[r], d, 64));
  }
  if (m32 == 0) {
#pragma unroll
    for (int r = 0; r < 16; ++r) {
      int ch = cg * 32 + (r & 3) + 8 * (r >> 2) + 4 * hi;
      if (ch < 100) srow[colbase + ch] = fmaxf(m[r] + bias[ch], 0.f);
    }
  }
}

// ---------------- K1: per-sentence conv+relu+maxpool -> sent[2048][304] f32 -------------------
__global__ void __launch_bounds__(512, 4)
conv_kernel(const int* __restrict__ tok, const __bf16* __restrict__ embh,
            const __bf16* __restrict__ Aw32,
            const float* __restrict__ b3, const float* __restrict__ b4, const float* __restrict__ b5,
            float* __restrict__ sent) {
  extern __shared__ __bf16 lds[];          // LDSBYTES (80256)
  char* ldsc = (char*)lds;
  const int sid = blockIdx.x, tid = threadIdx.x;
  const int* t0 = tok + sid * 128;
  const char* eb = (const char*)embh;
  // targeted zeroing: halo rows 128..131 (full) + per-row tail bytes [600,608)
  for (int i = tid; i < 4 * 76; i += 512) {
    int r = 128 + i / 76, q = i - (i / 76) * 76;
    *(uint2*)(ldsc + ((r * LDSROWB + q * 8) ^ ((r & 7) << 4))) = (uint2){0u, 0u};
  }
  if (tid < 128) {
    *(uint2*)(ldsc + ((tid * LDSROWB + 600) ^ ((tid & 7) << 4))) = (uint2){0u, 0u};
  }
  // gather: 75 uint2 (8B) per 600B bf16 row
  for (int i = tid; i < 128 * 75; i += 512) {
    int r = i / 75, q = i - r * 75;
    long tk = (long)t0[r];
    uint2 v = *(const uint2*)(eb + tk * 600L + q * 8);
    *(uint2*)(ldsc + ((r * LDSROWB + q * 8) ^ ((r & 7) << 4))) = v;
  }
  __syncthreads();
  const int wave = tid >> 6, lane = tid & 63;
  float* srow = sent + (size_t)sid * 304;
  // waves 0-3: conv5 cg=wave then conv3 cg=wave; waves 4-7: conv4 cg=wave-4.
  if (wave < 4) {
    conv_chunk1(ldsc, Aw32, 28, 5, wave, b5, 200, 123, srow, lane);
    conv_chunk1(ldsc, Aw32,  0, 3, wave, b3,   0, 125, srow, lane);
  } else {
    conv_chunk1(ldsc, Aw32, 12, 4, wave - 4, b4, 100, 124, srow, lane);
  }
}

// ---------------- K2: merged grid: blocks 0..511 = xig (4 rows) ; 512..527 = h0 (4 rows) ------
__global__ void xigh0_kernel(const float* __restrict__ sent,
                             const float* __restrict__ pw, const float* __restrict__ pb,
                             const float* __restrict__ wf, const float* __restrict__ wb,
                             const float* __restrict__ bif, const float* __restrict__ bhf,
                             const float* __restrict__ bib, const float* __restrict__ bhb,
                             const float* __restrict__ iw, const float* __restrict__ ib,
                             float* __restrict__ G, float* __restrict__ h0) {
  __shared__ float s[4][300];
  __shared__ float xi[4][304];
  const int tid = threadIdx.x;
  if (blockIdx.x < 512) {
    const int rb = blockIdx.x * 4;
    for (int i = tid; i < 4 * 300; i += 256) {
      int r = i / 300, c = i - r * 300;
      s[r][c] = sent[(size_t)(rb + r) * 304 + c];
    }
    __syncthreads();
    for (int o = tid; o < 300; o += 256) {
      const float* w = pw + o * 300;
      float bvv = pb[o];
      float a[4];
#pragma unroll
      for (int r = 0; r < 4; ++r) a[r] = bvv;
      for (int k = 0; k < 300; k += 4) {
        float4 wv = *(const float4*)(w + k);
#pragma unroll
        for (int r = 0; r < 4; ++r)
          a[r] += wv.x * s[r][k] + wv.y * s[r][k + 1] + wv.z * s[r][k + 2] + wv.w * s[r][k + 3];
      }
#pragma unroll
      for (int r = 0; r < 4; ++r) xi[r][o] = a[r];
    }
    __syncthreads();
    for (int o = tid; o < 1024; o += 256) {
      int dir = o >> 9, oo = o & 511;
      const float* w = (dir ? wb : wf) + oo * 300;
      float bvv = dir ? (bib[oo] + bhb[oo]) : (bif[oo] + bhf[oo]);
      float a[4];
#pragma unroll
      for (int r = 0; r < 4; ++r) a[r] = bvv;
      for (int k = 0; k < 300; k += 4) {
        float4 wv = *(const float4*)(w + k);
#pragma unroll
        for (int r = 0; r < 4; ++r)
          a[r] += wv.x * xi[r][k] + wv.y * xi[r][k + 1] + wv.z * xi[r][k + 2] + wv.w * xi[r][k + 3];
      }
#pragma unroll
      for (int r = 0; r < 4; ++r) G[(rb + r) * 1024 + o] = a[r];
    }
  } else {
    const int bb = (blockIdx.x - 512) * 4;
    for (int i = tid; i < 4 * 300; i += 256) {
      int r = i / 300, c = i - r * 300;
      s[r][c] = sent[(size_t)((bb + r) * 32) * 304 + c];
    }
    __syncthreads();
    for (int o = tid; o < 512; o += 256) {
      const float* w = iw + o * 300;
      float bvv = ib[o];
      float a[4];
#pragma unroll
      for (int r = 0; r < 4; ++r) a[r] = bvv;
      for (int k = 0; k < 300; k += 4) {
        float4 wv = *(const float4*)(w + k);
#pragma unroll
        for (int r = 0; r < 4; ++r)
          a[r] += wv.x * s[r][k] + wv.y * s[r][k + 1] + wv.z * s[r][k + 2] + wv.w * s[r][k + 3];
      }
#pragma unroll
      for (int r = 0; r < 4; ++r) h0[(bb + r) * 512 + o] = a[r];
    }
  }
}

// ---------------- K4: rnn v3 -- 64 blocks x 1024 thr, 2 chains/block, 4-way k-split -----------
#if __has_builtin(__builtin_amdgcn_fdot2)
#define FDOT2(a, b, c) __builtin_amdgcn_fdot2((a), (b), (c), false)
#else
static __device__ __forceinline__ float FDOT2(h2v a, h2v b, float c) {
  return c + (float)a[0] * (float)b[0] + (float)a[1] * (float)b[1];
}
#endif
__device__ __forceinline__ h2v as_h2(unsigned int u) { return __builtin_bit_cast(h2v, u); }

__global__ void __launch_bounds__(1024)
rnn_kernel(const uint4* __restrict__ Wq, const float* __restrict__ G,
           const float* __restrict__ h0, float* __restrict__ H) {
  const int blk = blockIdx.x, tid = threadIdx.x;
  const int dir = blk >> 5, b0 = (blk & 31) * 2;   // chains b0, b0+1
  const int o = tid & 255, kh = (tid >> 8) & 3;    // o-slot, k-quarter
  __shared__ float hs[2][512];
  __shared__ uint2 h2p[2][128];                    // h2p[c][kq] packs h[4kq..4kq+3]
  __shared__ float part[4][2][512];                // [kh][chain][out]
  {
    int c = tid >> 9, oo = tid & 511;
    hs[c][oo] = h0[(b0 + c) * 512 + oo];
  }
  __syncthreads();
  const uint4* W = Wq + (size_t)dir * (128 * 256);
  for (int t = 0; t < 32; ++t) {
    if (tid < 256) {
      int c = tid >> 7, kq = tid & 127;
      h2p[c][kq] = (uint2){packf16(hs[c][4 * kq], hs[c][4 * kq + 1]),
                           packf16(hs[c][4 * kq + 2], hs[c][4 * kq + 3])};
    }
    __syncthreads();
    float a00 = 0.f, a01 = 0.f, a10 = 0.f, a11 = 0.f;   // [chain][out-half]
    const int kb = kh * 32;
#pragma unroll 4
    for (int kk = 0; kk < 32; ++kk) {
      int kq = kb + kk;
      uint4 w = W[kq * 256 + o];                   // one W load feeds both chains
      uint2 p0 = h2p[0][kq], p1 = h2p[1][kq];
      a00 = FDOT2(as_h2(w.x), as_h2(p0.x), a00); a00 = FDOT2(as_h2(w.z), as_h2(p0.y), a00);
      a01 = FDOT2(as_h2(w.y), as_h2(p0.x), a01); a01 = FDOT2(as_h2(w.w), as_h2(p0.y), a01);
      a10 = FDOT2(as_h2(w.x), as_h2(p1.x), a10); a10 = FDOT2(as_h2(w.z), as_h2(p1.y), a10);
      a11 = FDOT2(as_h2(w.y), as_h2(p1.x), a11); a11 = FDOT2(as_h2(w.w), as_h2(p1.y), a11);
    }
    part[kh][0][o] = a00; part[kh][0][o + 256] = a01;
    part[kh][1][o] = a10; part[kh][1][o + 256] = a11;
    __syncthreads();
    {
      int c = tid >> 9, oo = tid & 511;
      const float* g = G + (size_t)((b0 + c) * 32 + t) * 1024 + dir * 512;
      float s = g[oo] + ((part[0][c][oo] + part[1][c][oo]) + (part[2][c][oo] + part[3][c][oo]));
      float n = tanhf(s);
      hs[c][oo] = n;
      H[(size_t)((dir * 64 + b0 + c) * 32 + t) * 512 + oo] = n;
    }
    __syncthreads();
  }
}

// ---------------- K5: preds = [hf;hb] @ cls_w^T + cls_b -> out[64][32][5] ---------------------
__global__ void pred_kernel(const float* __restrict__ H, const float* __restrict__ cw,
                            const float* __restrict__ cb, float* __restrict__ out) {
  const int bt = blockIdx.x * 4 + (threadIdx.x >> 6);   // 4 bt per 256-thread block
  const int lane = threadIdx.x & 63;
  const int b = bt >> 5, t = bt & 31;
  const float* hf = H + ((size_t)(b * 32 + t)) * 512;
  const float* hb = H + ((size_t)((64 + b) * 32 + t)) * 512;
  for (int c = 0; c < 5; ++c) {
    const float* w = cw + c * 1024;
    float a = 0.f;
    for (int o = lane; o < 512; o += 64) a += w[o] * hf[o] + w[512 + o] * hb[o];
#pragma unroll
    for (int d = 32; d; d >>= 1) a += __shfl_down(a, d, 64);
    if (lane == 0) out[bt * 5 + c] = a + cb[c];
  }
}

// ------------------------------------------------------------------------------------------------
extern "C" void kernel_launch(void* const* d_in, const int* in_sizes, int n_in,
                              void* d_out, int out_size, void* d_ws, size_t ws_size,
                              hipStream_t stream) {
  const int*   tok  = (const int*)d_in[0];
  const float* emb  = (const float*)d_in[1];
  const float* w3   = (const float*)d_in[2];
  const float* b3   = (const float*)d_in[3];
  const float* w4   = (const float*)d_in[4];
  const float* b4   = (const float*)d_in[5];
  const float* w5   = (const float*)d_in[6];
  const float* b5   = (const float*)d_in[7];
  const float* pw   = (const float*)d_in[8];
  const float* pb   = (const float*)d_in[9];
  const float* iw   = (const float*)d_in[10];
  const float* ib   = (const float*)d_in[11];
  const float* wihf = (const float*)d_in[12];
  const float* whhf = (const float*)d_in[13];
  const float* bihf = (const float*)d_in[14];
  const float* bhhf = (const float*)d_in[15];
  const float* wihb = (const float*)d_in[16];
  const float* whhb = (const float*)d_in[17];
  const float* bihb = (const float*)d_in[18];
  const float* bhhb = (const float*)d_in[19];
  const float* cw   = (const float*)d_in[20];
  const float* cb   = (const float*)d_in[21];
  float* out = (float*)d_out;

  // ws layout. embh (28.6MB) ALIASES the G/h0/H region: conv finishes reading
  // embh before xigh0/rnn write G/h0/H (stream-ordered), and prep_all rewrites
  // embh at the start of every call. Max ws use ~36.6MB.
  char* ws = (char*)d_ws;
  __bf16* Aw32  = (__bf16*)(ws);                        //  0MB: 48*19*512*2 = 934 KB
  uint4* Wq     = (uint4*)(ws +  1u * 1024 * 1024);     //  1MB: 1 MB
  float* sent   = (float*)(ws +  2u * 1024 * 1024);     //  2MB: 2048*304*4 = 2.49 MB
  __bf16* embh  = (__bf16*)(ws + 8u * 1024 * 1024);     //  8MB: 50000*300*2 = 28.6MB (alias)
  float* G      = (float*)(ws +  8u * 1024 * 1024);     //  8MB: 8 MB   (alias of embh)
  float* h0     = (float*)(ws + 16u * 1024 * 1024);     // 16MB: 128 KB (alias of embh)
  float* H      = (float*)(ws + 17u * 1024 * 1024);     // 17MB: 8.4 MB (alias of embh)

  prep_all<<<9405, 256, 0, stream>>>(emb, embh, w3, w4, w5, Aw32, whhf, whhb, Wq);

  hipFuncSetAttribute(reinterpret_cast<const void*>(conv_kernel),
                      hipFuncAttributeMaxDynamicSharedMemorySize, LDSBYTES);
  conv_kernel<<<2048, 512, LDSBYTES, stream>>>(tok, embh, Aw32, b3, b4, b5, sent);

  xigh0_kernel<<<528, 256, 0, stream>>>(sent, pw, pb, wihf, wihb, bihf, bhhf, bihb, bhhb,
                                        iw, ib, G, h0);
  rnn_kernel<<<64, 1024, 0, stream>>>(Wq, G, h0, H);
  pred_kernel<<<512, 256, 0, stream>>>(H, cw, cb, out);
}